// Round 13
// baseline (72.703 us; speedup 1.0000x reference)
//
#include <hip/hip_runtime.h>

typedef __attribute__((ext_vector_type(8))) short bf16x8;
typedef __attribute__((ext_vector_type(4))) float f32x4;

__device__ __forceinline__ unsigned short f2bf(float f) {
  unsigned int u = __float_as_uint(f);
  return (unsigned short)((u + 0x7fffu + ((u >> 16) & 1u)) >> 16);  // RNE
}

__device__ __forceinline__ float bf2f(unsigned short s) {
  return __uint_as_float(((unsigned int)s) << 16);
}

__device__ __forceinline__ void gload_lds16(const void* g, void* l) {
  __builtin_amdgcn_global_load_lds((const __attribute__((address_space(1))) void*)g,
                                   (__attribute__((address_space(3))) void*)l,
                                   16, 0, 0);
}

// prep: cast x, U, V fp32 -> bf16 in one grid-stride pass (float4/ushort4).
__global__ void prep(const float4* __restrict__ x, const float4* __restrict__ U,
                     const float4* __restrict__ V, ushort4* __restrict__ xb,
                     ushort4* __restrict__ Ub, ushort4* __restrict__ Vb) {
  const int NX = 4096 * 4096 / 4;  // 4194304
  const int NU = 256 * 4096 / 4;   // 262144 each for U and V
  int i = blockIdx.x * 256 + threadIdx.x;
  const int stride = gridDim.x * 256;
  for (; i < NX + 2 * NU; i += stride) {
    const float4* s; ushort4* d; int j;
    if (i < NX)           { s = x; d = xb; j = i; }
    else if (i < NX + NU) { s = U; d = Ub; j = i - NX; }
    else                  { s = V; d = Vb; j = i - NX - NU; }
    float4 v = s[j];
    ushort4 o;
    o.x = f2bf(v.x); o.y = f2bf(v.y); o.z = f2bf(v.z); o.w = f2bf(v.w);
    d[j] = o;
  }
}

// ---------------------------------------------------------------------------
// GEMM1 (proven R12 skeleton, all-bf16), now at 4 blocks/CU via z split:
//   P[z][m][r] = sum_{k in chunk z} xb[m,k] * Ub[r,k]   (bf16 partials)
// BM=64, BN=256, BK=32. Waves 1x4 (wave tile 64x64, 16 MFMA vs 8 ds_read
// per step). LDS 40KB -> capacity 4 blocks/CU; grid 64 x nz fills it when
// nz=16 (1024 blocks). XOR-swizzle both-sides on both tiles.
// ---------------------------------------------------------------------------
__global__ __launch_bounds__(256)
void gemm1_bf16(const unsigned short* __restrict__ A,   // xb [4096][4096]
                const unsigned short* __restrict__ B,   // Ub [256][4096]
                unsigned short* __restrict__ P,
                int kChunk, int nkt) {
  __shared__ __align__(16) unsigned short sA[2][64 * 32];    // 2 x 4 KB
  __shared__ __align__(16) unsigned short sB[2][256 * 32];   // 2 x 16 KB

  const int tid = threadIdx.x;
  const int l = tid & 63;
  const int w = tid >> 6;
  const int wn = w * 64;           // 1x4 waves: wm = 0
  const int rm = blockIdx.x * 64;
  const int k0base = blockIdx.z * kChunk;
  const int lr = l & 15;
  const int lg = l >> 4;

  auto stage = [&](int kt, int buf) {
    const int k0 = k0base + kt * 32;
    // B: 1024 slots of 16B. slot s: row r=s>>2, swizzled col 8*((s&3)^(r&3)).
#pragma unroll
    for (int is = 0; is < 4; ++is) {
      int s = is * 256 + tid;
      int r = s >> 2;
      gload_lds16(B + (long long)r * 4096 + k0 + 8 * ((s & 3) ^ (r & 3)),
                  (char*)sB[buf] + s * 16);
    }
    // A: 256 slots. same swizzle.
    {
      int s = tid;
      int r = s >> 2;
      gload_lds16(A + (long long)(rm + r) * 4096 + k0 + 8 * ((s & 3) ^ (r & 3)),
                  (char*)sA[buf] + s * 16);
    }
  };

  f32x4 acc[4][4] = {};

  stage(0, 0);
  for (int kt = 0; kt < nkt; ++kt) {
    __syncthreads();  // tile kt resident; prev reads done
    if (kt + 1 < nkt) stage(kt + 1, (kt + 1) & 1);
    const char* a0 = (const char*)sA[kt & 1];
    const char* b0 = (const char*)sB[kt & 1];
    bf16x8 af[4], bfr[4];
#pragma unroll
    for (int m = 0; m < 4; ++m) {
      const int row = m * 16 + lr;
      af[m] = *(const bf16x8*)(a0 + row * 64 + ((lg * 16) ^ ((row & 3) << 4)));
    }
#pragma unroll
    for (int n = 0; n < 4; ++n) {
      const int row = wn + n * 16 + lr;
      bfr[n] = *(const bf16x8*)(b0 + row * 64 + ((lg * 16) ^ ((row & 3) << 4)));
    }
#pragma unroll
    for (int m = 0; m < 4; ++m)
#pragma unroll
      for (int n = 0; n < 4; ++n)
        acc[m][n] = __builtin_amdgcn_mfma_f32_16x16x32_bf16(af[m], bfr[n], acc[m][n], 0, 0, 0);
  }

  // Epilogue: bf16 partials. C/D: col = lane&15, row = (lane>>4)*4 + reg.
  unsigned short* Pz = P + (long long)blockIdx.z * (4096LL * 256);
  const int r0 = rm + lg * 4;
#pragma unroll
  for (int n = 0; n < 4; ++n) {
    const int cc = wn + n * 16 + lr;
#pragma unroll
    for (int m = 0; m < 4; ++m)
#pragma unroll
      for (int i = 0; i < 4; ++i)
        Pz[(long long)(r0 + m * 16 + i) * 256 + cc] = f2bf(acc[m][n][i]);
  }
}

// Sum nz bf16 split-K partial slices -> bf16 t, IN PLACE over slice 0.
// Safe: thread i is the only reader/writer of index i in slice 0, and it
// writes after reading all slices.
__global__ void reduceN(ushort4* __restrict__ P, int nz) {
  const int S = 4096 * 256 / 4;  // 262144 ushort4 per slice
  int i = blockIdx.x * 256 + threadIdx.x;
  float sx = 0, sy = 0, sz = 0, sw = 0;
  for (int z = 0; z < nz; ++z) {
    ushort4 v = P[i + z * S];
    sx += bf2f(v.x); sy += bf2f(v.y); sz += bf2f(v.z); sw += bf2f(v.w);
  }
  ushort4 o;
  o.x = f2bf(sx); o.y = f2bf(sy); o.z = f2bf(sz); o.w = f2bf(sw);
  P[i] = o;
}

// ---------------------------------------------------------------------------
// GEMM2 (unchanged, proven ~write-floor): out = t @ V^T + bias, fp32 out.
// BM=BN=128, nkt=8, XOR-swizzled both-sides.
// ---------------------------------------------------------------------------
__global__ __launch_bounds__(256)
void gemm2(const unsigned short* __restrict__ A,
           const unsigned short* __restrict__ B,
           const float* __restrict__ bias,
           float* __restrict__ C) {
  __shared__ __align__(16) unsigned short sA[2][128 * 32];
  __shared__ __align__(16) unsigned short sB[2][128 * 32];

  const int tid = threadIdx.x;
  const int l = tid & 63;
  const int w = tid >> 6;
  const int wm = (w >> 1) * 64;
  const int wn = (w & 1) * 64;
  const int rm = blockIdx.x * 128;
  const int rn = blockIdx.y * 128;
  const int lr = l & 15;
  const int lg = l >> 4;

  auto stage = [&](int kt, int buf) {
    const int k0 = kt * 32;
#pragma unroll
    for (int is = 0; is < 2; ++is) {
      int s = is * 256 + tid;
      int r = s >> 2;
      gload_lds16(B + (long long)(rn + r) * 256 + k0 + 8 * ((s & 3) ^ (r & 3)),
                  (char*)sB[buf] + s * 16);
    }
#pragma unroll
    for (int is = 0; is < 2; ++is) {
      int s = is * 256 + tid;
      int r = s >> 2;
      gload_lds16(A + (long long)(rm + r) * 256 + k0 + 8 * ((s & 3) ^ (r & 3)),
                  (char*)sA[buf] + s * 16);
    }
  };

  f32x4 acc[4][4] = {};

  stage(0, 0);
  for (int kt = 0; kt < 8; ++kt) {
    __syncthreads();
    if (kt < 7) stage(kt + 1, (kt + 1) & 1);
    const char* a0 = (const char*)sA[kt & 1];
    const char* b0 = (const char*)sB[kt & 1];
    bf16x8 af[4], bfr[4];
#pragma unroll
    for (int m = 0; m < 4; ++m) {
      const int row = wm + m * 16 + lr;
      af[m] = *(const bf16x8*)(a0 + row * 64 + ((lg * 16) ^ ((row & 3) << 4)));
    }
#pragma unroll
    for (int n = 0; n < 4; ++n) {
      const int row = wn + n * 16 + lr;
      bfr[n] = *(const bf16x8*)(b0 + row * 64 + ((lg * 16) ^ ((row & 3) << 4)));
    }
#pragma unroll
    for (int m = 0; m < 4; ++m)
#pragma unroll
      for (int n = 0; n < 4; ++n)
        acc[m][n] = __builtin_amdgcn_mfma_f32_16x16x32_bf16(af[m], bfr[n], acc[m][n], 0, 0, 0);
  }

  const int r0 = rm + wm + lg * 4;
  const int c0 = rn + wn + lr;
#pragma unroll
  for (int n = 0; n < 4; ++n) {
    const int cc = c0 + n * 16;
    const float badd = bias[cc];
#pragma unroll
    for (int m = 0; m < 4; ++m)
#pragma unroll
      for (int i = 0; i < 4; ++i)
        C[(long long)(r0 + m * 16 + i) * 4096 + cc] = acc[m][n][i] + badd;
  }
}

extern "C" void kernel_launch(void* const* d_in, const int* in_sizes, int n_in,
                              void* d_out, int out_size, void* d_ws, size_t ws_size,
                              hipStream_t stream) {
  const float* x    = (const float*)d_in[0];  // [4096,4096]
  const float* U    = (const float*)d_in[1];  // [256,4096]
  const float* V    = (const float*)d_in[2];  // [4096,256]
  const float* bias = (const float*)d_in[3];  // [4096]
  float* out = (float*)d_out;                 // [4096,4096] fp32

  // nz = split-K factor. Prefer 16 (4 blocks/CU in gemm1); needs 68 MB ws.
  const int nz = (ws_size >= (69ull << 20)) ? 16 : 8;
  const size_t pBytes = (size_t)nz * 4096 * 256 * 2;  // bf16 partials

  // Workspace layout (nz=16: 68 MB; nz=8: 52 MB):
  //  [0, pBytes)            P partials; slice 0 becomes t after reduceN
  //  [pBytes, +2MB)         U bf16
  //  [pBytes+2MB, +2MB)     V bf16
  //  [pBytes+4MB, +32MB)    xb bf16
  char* ws = (char*)d_ws;
  unsigned short* P  = (unsigned short*)ws;
  unsigned short* Ub = (unsigned short*)(ws + pBytes);
  unsigned short* Vb = (unsigned short*)(ws + pBytes + (2ull << 20));
  unsigned short* xb = (unsigned short*)(ws + pBytes + (4ull << 20));
  unsigned short* tb = P;  // in-place reduce target

  prep<<<2048, 256, 0, stream>>>((const float4*)x, (const float4*)U, (const float4*)V,
                                 (ushort4*)xb, (ushort4*)Ub, (ushort4*)Vb);

  // GEMM1: grid 64 M-blocks x nz. nz=16 -> 1024 blocks = 4/CU resident.
  dim3 g1(64, 1, nz);
  gemm1_bf16<<<g1, 256, 0, stream>>>(xb, Ub, P, 4096 / nz, 128 / nz);

  reduceN<<<1024, 256, 0, stream>>>((ushort4*)P, nz);

  // GEMM2: grid 32x32.
  dim3 g2(32, 32, 1);
  gemm2<<<g2, 256, 0, stream>>>(tb, Vb, bias, out);
}

// Round 15
// 57.580 us; speedup vs baseline: 1.2626x; 1.2626x over previous
//
#include <hip/hip_runtime.h>

typedef __attribute__((ext_vector_type(8))) short bf16x8;
typedef __attribute__((ext_vector_type(4))) float f32x4;

__device__ __forceinline__ unsigned short f2bf(float f) {
  unsigned int u = __float_as_uint(f);
  return (unsigned short)((u + 0x7fffu + ((u >> 16) & 1u)) >> 16);  // RNE
}

__device__ __forceinline__ float bf2f(unsigned short s) {
  return __uint_as_float(((unsigned int)s) << 16);
}

__device__ __forceinline__ void gload_lds16(const void* g, void* l) {
  __builtin_amdgcn_global_load_lds((const __attribute__((address_space(1))) void*)g,
                                   (__attribute__((address_space(3))) void*)l,
                                   16, 0, 0);
}

// Cast U, V fp32 -> bf16 (12 MB total traffic, ~2.5us).
__global__ void castUV(const float4* __restrict__ U, const float4* __restrict__ V,
                       ushort4* __restrict__ Ub, ushort4* __restrict__ Vb) {
  const int NU = 256 * 4096 / 4;  // 262144 float4 each
  int i = blockIdx.x * 256 + threadIdx.x;
  const float4* s; ushort4* d; int j;
  if (i < NU) { s = U; d = Ub; j = i; }
  else        { s = V; d = Vb; j = i - NU; }
  float4 v = s[j];
  ushort4 o;
  o.x = f2bf(v.x); o.y = f2bf(v.y); o.z = f2bf(v.z); o.w = f2bf(v.w);
  d[j] = o;
}

// ---------------------------------------------------------------------------
// GEMM1 (R6-proven, session-best config), deep-pipelined:
//   P[z][m][r] = sum_k x[m, z*512+k] * U[r, z*512+k]
// x fp32 read ONCE (cast fused in-register), U bf16, P bf16 partials.
// BM=64, BN=256, BK=32, NKT=16. 4 waves (2x2), wave tile 32x128.
// A: global->reg 4 ahead (4 rotating reg sets), cvt+ds_write 1 ahead (mod-3
// sA). B: global_load_lds 2 ahead (mod-4 sB). One raw s_barrier per step with
// counted s_waitcnt vmcnt(12) — never vmcnt(0). Clamped issues keep counts
// uniform. NEW vs R6: s_setprio(1) around the MFMA cluster (T5 — pipeline has
// wave role-diversity, the documented prerequisite).
// ---------------------------------------------------------------------------
template <int NKT>
__global__ __launch_bounds__(256, 2)
void gemm1_pipe(const float* __restrict__ x, const unsigned short* __restrict__ U,
                unsigned short* __restrict__ P) {
  __shared__ unsigned short sA[3][64 * 32];    // 3 x 4 KB
  __shared__ unsigned short sB[4][256 * 32];   // 4 x 16 KB  (total 76 KB)

  const int tid = threadIdx.x;
  const int l = tid & 63;
  const int w = tid >> 6;
  const int wm = (w >> 1) * 32;    // wave M offset (MREP=2)
  const int wn = (w & 1) * 128;    // wave N offset (NREP=8)
  const int rm = blockIdx.x * 64;
  const int k0base = blockIdx.z * (NKT * 32);
  const int lr = l & 15;
  const int lc8 = (l >> 4) * 8;

  const float* xs = x + (long long)(rm + (tid >> 2)) * 4096 + k0base + (tid & 3) * 8;

  float4 ar[4][2];  // rotating A reg sets (static-indexed under full unroll)

  auto GA = [&](int j, int slot) {
    const float* s = xs + j * 32;
    ar[slot][0] = *(const float4*)s;
    ar[slot][1] = *(const float4*)(s + 4);
  };
  auto WR = [&](int jbuf, int slot) {  // cvt + ds_write into sA[jbuf%3]
    float4 v0 = ar[slot][0], v1 = ar[slot][1];
    ushort4 o0, o1;
    o0.x = f2bf(v0.x); o0.y = f2bf(v0.y); o0.z = f2bf(v0.z); o0.w = f2bf(v0.w);
    o1.x = f2bf(v1.x); o1.y = f2bf(v1.y); o1.z = f2bf(v1.z); o1.w = f2bf(v1.w);
    ushort4* d = (ushort4*)&sA[jbuf % 3][tid * 8];
    d[0] = o0; d[1] = o1;
  };
  auto GB = [&](int jdata, int jbuf) {  // 4x gload_lds into sB[jbuf%4]
    const int k0 = k0base + jdata * 32;
#pragma unroll
    for (int is = 0; is < 4; ++is) {
      int eo = is * 2048 + tid * 8;
      gload_lds16(U + (long long)(eo >> 5) * 4096 + k0 + (eo & 31),
                  &sB[jbuf % 4][eo]);
    }
  };

  f32x4 acc[2][8] = {};

  // Prologue — mimics steady state: GA0 GA1 GA2 GB0 GA3 GB1, W(0)
  GA(0, 0); GA(1, 1); GA(2, 2);
  GB(0, 0);
  GA(3, 3);
  GB(1, 1);
  WR(0, 0);  // compiler auto-waits GA(0)

#pragma unroll
  for (int j = 0; j < NKT; ++j) {
    GA((j + 4 < NKT) ? (j + 4) : (NKT - 1), (j + 4) & 3);  // clamped
    WR(j + 1, (j + 1) & 3);                                 // auto-waits its GA
    GB((j + 2 < NKT) ? (j + 2) : (NKT - 1), j + 2);         // clamped
    asm volatile("s_waitcnt vmcnt(12) lgkmcnt(0)" ::: "memory");
    __builtin_amdgcn_sched_barrier(0);
    __builtin_amdgcn_s_barrier();
    __builtin_amdgcn_sched_barrier(0);
    const unsigned short* a0 = sA[j % 3];
    const unsigned short* b0 = sB[j % 4];
    bf16x8 af[2], bf[8];
#pragma unroll
    for (int m = 0; m < 2; ++m)
      af[m] = *(const bf16x8*)&a0[(wm + m * 16 + lr) * 32 + lc8];
#pragma unroll
    for (int n = 0; n < 8; ++n)
      bf[n] = *(const bf16x8*)&b0[(wn + n * 16 + lr) * 32 + lc8];
    __builtin_amdgcn_s_setprio(1);
#pragma unroll
    for (int m = 0; m < 2; ++m)
#pragma unroll
      for (int n = 0; n < 8; ++n)
        acc[m][n] = __builtin_amdgcn_mfma_f32_16x16x32_bf16(af[m], bf[n], acc[m][n], 0, 0, 0);
    __builtin_amdgcn_s_setprio(0);
  }

  // Epilogue: bf16 partials. C/D layout: col = lane&15, row = (lane>>4)*4 + reg.
  unsigned short* Cb = P + (long long)blockIdx.z * (4096LL * 256);
  const int r0 = rm + wm + (l >> 4) * 4;
  const int c0 = wn + lr;
#pragma unroll
  for (int n = 0; n < 8; ++n) {
    const int cc = c0 + n * 16;
#pragma unroll
    for (int m = 0; m < 2; ++m)
#pragma unroll
      for (int i = 0; i < 4; ++i)
        Cb[(long long)(r0 + m * 16 + i) * 256 + cc] = f2bf(acc[m][n][i]);
  }
}

// ---------------------------------------------------------------------------
// GEMM2 (R6-proven): out = t @ V^T + bias, fp32 out. BM=BN=128, nkt=8.
// ---------------------------------------------------------------------------
template <int MREP, int NREP>
__global__ __launch_bounds__(256)
void gemm_nt(const unsigned short* __restrict__ A,
             const unsigned short* __restrict__ B,
             const float* __restrict__ bias,
             float* __restrict__ C,
             int lda, int ldb, int ldc, int nkt) {
  constexpr int BM = 32 * MREP;
  constexpr int BN = 32 * NREP;
  constexpr int ISS_A = BM / 64;
  constexpr int ISS_B = BN / 64;

  __shared__ unsigned short sA[2][BM * 32];
  __shared__ unsigned short sB[2][BN * 32];

  const int tid = threadIdx.x;
  const int l = tid & 63;
  const int w = tid >> 6;
  const int wm = (w >> 1) * (MREP * 16);
  const int wn = (w & 1) * (NREP * 16);
  const int rm = blockIdx.x * BM;
  const int rn = blockIdx.y * BN;

  const int lr = l & 15;
  const int lc8 = (l >> 4) * 8;

  auto stage = [&](int kt, int buf) {
    const int k0 = kt * 32;
#pragma unroll
    for (int is = 0; is < ISS_B; ++is) {
      int eo = is * 2048 + tid * 8;
      int r = eo >> 5, c = eo & 31;
      gload_lds16(B + (long long)(rn + r) * ldb + k0 + c, &sB[buf][eo]);
    }
#pragma unroll
    for (int is = 0; is < ISS_A; ++is) {
      int eo = is * 2048 + tid * 8;
      int r = eo >> 5, c = eo & 31;
      gload_lds16(A + (long long)(rm + r) * lda + k0 + c, &sA[buf][eo]);
    }
  };

  f32x4 acc[MREP][NREP] = {};

  stage(0, 0);
  for (int kt = 0; kt < nkt; ++kt) {
    __syncthreads();
    if (kt + 1 < nkt) stage(kt + 1, (kt + 1) & 1);
    const unsigned short* a0 = sA[kt & 1];
    const unsigned short* b0 = sB[kt & 1];
    bf16x8 af[MREP], bfr[NREP];
#pragma unroll
    for (int m = 0; m < MREP; ++m)
      af[m] = *(const bf16x8*)&a0[(wm + m * 16 + lr) * 32 + lc8];
#pragma unroll
    for (int n = 0; n < NREP; ++n)
      bfr[n] = *(const bf16x8*)&b0[(wn + n * 16 + lr) * 32 + lc8];
#pragma unroll
    for (int m = 0; m < MREP; ++m)
#pragma unroll
      for (int n = 0; n < NREP; ++n)
        acc[m][n] = __builtin_amdgcn_mfma_f32_16x16x32_bf16(af[m], bfr[n], acc[m][n], 0, 0, 0);
  }

  const int r0 = rm + wm + (l >> 4) * 4;
  const int c0 = rn + wn + lr;
#pragma unroll
  for (int n = 0; n < NREP; ++n) {
    const int cc = c0 + n * 16;
    const float badd = bias[cc];
#pragma unroll
    for (int m = 0; m < MREP; ++m)
#pragma unroll
      for (int i = 0; i < 4; ++i)
        C[(long long)(r0 + m * 16 + i) * ldc + cc] = acc[m][n][i] + badd;
  }
}

// Sum 8 bf16 split-K partial slices -> bf16 t (fp32 accumulate)
__global__ void reduce8(const ushort4* __restrict__ P, ushort4* __restrict__ t) {
  const int S = 4096 * 256 / 4;  // 262144 ushort4 per slice
  int i = blockIdx.x * 256 + threadIdx.x;
  float sx = 0, sy = 0, sz = 0, sw = 0;
#pragma unroll
  for (int z = 0; z < 8; ++z) {
    ushort4 v = P[i + z * S];
    sx += bf2f(v.x); sy += bf2f(v.y); sz += bf2f(v.z); sw += bf2f(v.w);
  }
  ushort4 o;
  o.x = f2bf(sx); o.y = f2bf(sy); o.z = f2bf(sz); o.w = f2bf(sw);
  t[i] = o;
}

extern "C" void kernel_launch(void* const* d_in, const int* in_sizes, int n_in,
                              void* d_out, int out_size, void* d_ws, size_t ws_size,
                              hipStream_t stream) {
  const float* x    = (const float*)d_in[0];  // [4096,4096]
  const float* U    = (const float*)d_in[1];  // [256,4096]
  const float* V    = (const float*)d_in[2];  // [4096,256]
  const float* bias = (const float*)d_in[3];  // [4096]
  float* out = (float*)d_out;                 // [4096,4096] fp32

  // Workspace layout (22 MB):
  //  [0,16MB)   P: bf16 split-K partials [8][4096][256]
  //  [16,18MB)  t bf16 [4096][256]
  //  [18,20MB)  U bf16 [256][4096]
  //  [20,22MB)  V bf16 [4096][256]
  char* ws = (char*)d_ws;
  unsigned short* P   = (unsigned short*)ws;
  unsigned short* tb  = (unsigned short*)(ws + (16u << 20));
  unsigned short* Ub  = (unsigned short*)(ws + (18u << 20));
  unsigned short* Vb  = (unsigned short*)(ws + (20u << 20));

  castUV<<<2048, 256, 0, stream>>>((const float4*)U, (const float4*)V,
                                   (ushort4*)Ub, (ushort4*)Vb);

  // GEMM1: grid 64 M-blocks x 8 split-K, 512 blocks (2/CU), NKT=16 steps.
  dim3 g1(4096 / 64, 1, 8);
  gemm1_pipe<16><<<g1, 256, 0, stream>>>(x, Ub, P);

  reduce8<<<(4096 * 256 / 4) / 256, 256, 0, stream>>>((const ushort4*)P, (ushort4*)tb);

  // GEMM2: out = t @ V^T + bias. BM=BN=128, grid 32x32, fp32 out.
  dim3 g2(4096 / 128, 4096 / 128, 1);
  gemm_nt<4, 4><<<g2, 256, 0, stream>>>(tb, Vb, bias, out, 256, 256, 4096, 8);
}